// Round 1
// baseline (622.015 us; speedup 1.0000x reference)
//
#include <hip/hip_runtime.h>
#include <hip/hip_bf16.h>
#include <stdint.h>

// Problem constants (from setup_inputs): B=4, S=2048, IN=4096, OUT=4096, R=16
#define M_DIM 8192   // B*S
#define N_DIM 4096   // OUT
#define K_DIM 4096   // IN
#define R_DIM 16
// SCALING = 32/16 = 2.0

typedef __attribute__((ext_vector_type(8))) short bf16x8;   // 8 bf16 = 4 VGPRs (A/B frag)
typedef __attribute__((ext_vector_type(4))) float f32x4;    // C/D frag

__device__ __forceinline__ unsigned short f2bf(float f) {
  union { float f; unsigned int u; } v; v.f = f;
  unsigned int r = 0x7FFFu + ((v.u >> 16) & 1u);   // round-to-nearest-even
  return (unsigned short)((v.u + r) >> 16);
}

// async 16B/lane global -> LDS (wave-uniform LDS base + lane*16 scatter)
__device__ __forceinline__ void gload16(const unsigned short* g, unsigned short* l) {
  __builtin_amdgcn_global_load_lds(
      (const __attribute__((address_space(1))) void*)g,
      (__attribute__((address_space(3))) void*)l,
      16, 0, 0);
}

// ---------------- kernel 1: cast x (fp32 -> bf16) ----------------
__global__ void cast_x_kernel(const float4* __restrict__ in,
                              ushort4* __restrict__ out, int n4) {
  int i = blockIdx.x * 256 + threadIdx.x;
  if (i < n4) {
    float4 f = in[i];
    ushort4 o;
    o.x = f2bf(f.x); o.y = f2bf(f.y); o.z = f2bf(f.z); o.w = f2bf(f.w);
    out[i] = o;
  }
}

// ---------------- kernel 2: W' = W + 2*(B@A), rownorm, scale ----------------
__global__ void prep_w_kernel(const float* __restrict__ W,
                              const float* __restrict__ Aw,   // [R, K]
                              const float* __restrict__ Bw,   // [N, R]
                              const float* __restrict__ mag,  // [N]
                              unsigned short* __restrict__ wbf,
                              float* __restrict__ scale) {
  const int o = blockIdx.x;
  const int tid = threadIdx.x;
  __shared__ float Bo[R_DIM];
  __shared__ float red[4];
  if (tid < R_DIM) Bo[tid] = Bw[o * R_DIM + tid];
  __syncthreads();
  float ss = 0.f;
  const size_t rowoff = (size_t)o * K_DIM;
  for (int i = tid; i < K_DIM; i += 256) {
    float v = W[rowoff + i];
    float acc = 0.f;
    #pragma unroll
    for (int r = 0; r < R_DIM; ++r) acc += Bo[r] * Aw[r * K_DIM + i];
    v += 2.0f * acc;           // SCALING = 2.0
    ss += v * v;
    wbf[rowoff + i] = f2bf(v);
  }
  #pragma unroll
  for (int off = 32; off > 0; off >>= 1) ss += __shfl_down(ss, off, 64);
  if ((tid & 63) == 0) red[tid >> 6] = ss;
  __syncthreads();
  if (tid == 0)
    scale[o] = mag[o] / sqrtf(red[0] + red[1] + red[2] + red[3]);
}

// ---------------- kernel 3: GEMM C[m,n] = scale[n] * sum_k A[m,k]*Bt[n,k] ----
// m97 structure: 128x128 tile, BK=32, 4 waves (2x2), each wave 4x4 of 16x16x32.
__global__ void __launch_bounds__(256)
dora_gemm(const unsigned short* __restrict__ A,   // [M, K] bf16
          const unsigned short* __restrict__ Bt,  // [N, K] bf16 (W', row-major = B^T layout)
          const float* __restrict__ scale,        // [N]
          float* __restrict__ C) {                // [M, N] fp32
  __shared__ __align__(16) unsigned short As[128 * 32];
  __shared__ __align__(16) unsigned short Bs[128 * 32];
  const int tid  = threadIdx.x;
  const int lane = tid & 63;
  const int wave = tid >> 6;
  const int bM = blockIdx.y * 128;
  const int bN = blockIdx.x * 128;

  // staging: 8 chunks of 1KiB per tile; wave w does chunks {2w,2w+1} of A and B.
  // lane l -> row c*16 + l/4, cols (l&3)*8 .. +7 (16B), LDS dest = chunkbase + l*16
  const int sr = lane >> 2;
  const int sc = (lane & 3) * 8;
  const unsigned short* pa0 = A  + (size_t)(bM + wave * 32 + sr) * K_DIM + sc;
  const unsigned short* pa1 = pa0 + (size_t)16 * K_DIM;
  const unsigned short* pb0 = Bt + (size_t)(bN + wave * 32 + sr) * K_DIM + sc;
  const unsigned short* pb1 = pb0 + (size_t)16 * K_DIM;
  unsigned short* lA0 = &As[wave * 32 * 32];
  unsigned short* lA1 = lA0 + 16 * 32;
  unsigned short* lB0 = &Bs[wave * 32 * 32];
  unsigned short* lB1 = lB0 + 16 * 32;

  // fragment indexing: A[m=lane&15][k=(lane>>4)*8+j]
  const int fr = lane & 15;
  const int fq = lane >> 4;
  const int wM = (wave >> 1) * 64;
  const int wN = (wave & 1) * 64;

  f32x4 acc[4][4];
  #pragma unroll
  for (int i = 0; i < 4; ++i)
    #pragma unroll
    for (int j = 0; j < 4; ++j) acc[i][j] = (f32x4){0.f, 0.f, 0.f, 0.f};

  for (int k0 = 0; k0 < K_DIM; k0 += 32) {
    gload16(pa0 + k0, lA0);
    gload16(pa1 + k0, lA1);
    gload16(pb0 + k0, lB0);
    gload16(pb1 + k0, lB1);
    __syncthreads();   // drains vmcnt before barrier (compiler-inserted)
    bf16x8 aF[4], bF[4];
    #pragma unroll
    for (int mt = 0; mt < 4; ++mt)
      aF[mt] = *(const bf16x8*)&As[(wM + mt * 16 + fr) * 32 + fq * 8];
    #pragma unroll
    for (int nt = 0; nt < 4; ++nt)
      bF[nt] = *(const bf16x8*)&Bs[(wN + nt * 16 + fr) * 32 + fq * 8];
    #pragma unroll
    for (int mt = 0; mt < 4; ++mt)
      #pragma unroll
      for (int nt = 0; nt < 4; ++nt)
        acc[mt][nt] = __builtin_amdgcn_mfma_f32_16x16x32_bf16(aF[mt], bF[nt], acc[mt][nt], 0, 0, 0);
    __syncthreads();
  }

  // epilogue: C/D layout col=lane&15, row=(lane>>4)*4+reg  [m89-verified]
  float scv[4];
  #pragma unroll
  for (int nt = 0; nt < 4; ++nt) scv[nt] = scale[bN + wN + nt * 16 + fr];
  #pragma unroll
  for (int mt = 0; mt < 4; ++mt) {
    const int m0 = bM + wM + mt * 16 + fq * 4;
    #pragma unroll
    for (int nt = 0; nt < 4; ++nt) {
      const int n = bN + wN + nt * 16 + fr;
      #pragma unroll
      for (int r = 0; r < 4; ++r)
        C[(size_t)(m0 + r) * N_DIM + n] = acc[mt][nt][r] * scv[nt];
    }
  }
}

extern "C" void kernel_launch(void* const* d_in, const int* in_sizes, int n_in,
                              void* d_out, int out_size, void* d_ws, size_t ws_size,
                              hipStream_t stream) {
  const float* x   = (const float*)d_in[0];   // [4,2048,4096]
  const float* W   = (const float*)d_in[1];   // [4096,4096]
  const float* la  = (const float*)d_in[2];   // [16,4096]
  const float* lb  = (const float*)d_in[3];   // [4096,16]
  const float* mag = (const float*)d_in[4];   // [4096]
  float* out = (float*)d_out;

  // workspace layout: x_bf16 (64 MiB) | w_bf16 (32 MiB) | scale (16 KiB)
  unsigned short* xbf = (unsigned short*)d_ws;
  unsigned short* wbf = (unsigned short*)((char*)d_ws + (size_t)M_DIM * K_DIM * 2);
  float* scale = (float*)((char*)d_ws + (size_t)M_DIM * K_DIM * 2 + (size_t)N_DIM * K_DIM * 2);

  const int n4 = (M_DIM * K_DIM) / 4;
  cast_x_kernel<<<(n4 + 255) / 256, 256, 0, stream>>>((const float4*)x, (ushort4*)xbf, n4);
  prep_w_kernel<<<N_DIM, 256, 0, stream>>>(W, la, lb, mag, wbf, scale);
  dim3 grid(N_DIM / 128, M_DIM / 128);
  dora_gemm<<<grid, 256, 0, stream>>>(xbf, wbf, scale, out);
}

// Round 2
// 595.200 us; speedup vs baseline: 1.0451x; 1.0451x over previous
//
#include <hip/hip_runtime.h>
#include <hip/hip_bf16.h>
#include <stdint.h>

// Problem constants: B=4, S=2048, IN=OUT=4096, R=16, SCALING=2.0
#define M_DIM 8192   // B*S
#define N_DIM 4096   // OUT
#define K_DIM 4096   // IN
#define R_DIM 16

#define PREP_BLOCKS 256         // 16 W-rows per block
#define CAST_BLOCKS 8192        // each thread casts 4 float4 (16 elems)

typedef __attribute__((ext_vector_type(8))) short bf16x8;   // A/B frag (4 VGPRs)
typedef __attribute__((ext_vector_type(4))) float f32x4;    // C/D frag

__device__ __forceinline__ unsigned short f2bf(float f) {
  union { float f; unsigned int u; } v; v.f = f;
  unsigned int r = 0x7FFFu + ((v.u >> 16) & 1u);   // RNE
  return (unsigned short)((v.u + r) >> 16);
}

__device__ __forceinline__ void gload16(const unsigned short* g, unsigned short* l) {
  __builtin_amdgcn_global_load_lds(
      (const __attribute__((address_space(1))) void*)g,
      (__attribute__((address_space(3))) void*)l,
      16, 0, 0);
}

// ------------- merged prep: [0,PREP_BLOCKS) = W'+scale, rest = cast x -------------
__global__ void __launch_bounds__(256) prep_kernel(
    const float4* __restrict__ x4, ushort4* __restrict__ xbf4,
    const float* __restrict__ W, const float* __restrict__ Aw,
    const float* __restrict__ Bw, const float* __restrict__ mag,
    unsigned short* __restrict__ wbf, float* __restrict__ scale) {
  const int tid = threadIdx.x;

  if (blockIdx.x >= PREP_BLOCKS) {
    // ---- cast x: fp32 -> bf16, 4x float4 per thread ----
    const int base = (blockIdx.x - PREP_BLOCKS) * 1024 + tid;
    #pragma unroll
    for (int u = 0; u < 4; ++u) {
      const int i = base + u * 256;
      float4 f = x4[i];
      ushort4 o;
      o.x = f2bf(f.x); o.y = f2bf(f.y); o.z = f2bf(f.z); o.w = f2bf(f.w);
      xbf4[i] = o;
    }
    return;
  }

  // ---- prep W' = W + 2*(B@A) for 16 rows; row norms; scale ----
  __shared__ float AwS[16 * 1024];   // 64 KiB chunk of Aw
  __shared__ float BoS[16 * 16];     // Bw rows for our 16 output rows
  __shared__ float red[16 * 4];
  const int o0 = blockIdx.x * 16;

  BoS[tid] = Bw[(o0 + (tid >> 4)) * R_DIM + (tid & 15)];

  float ss[16];
  #pragma unroll
  for (int i = 0; i < 16; ++i) ss[i] = 0.f;

  const float4* W4  = (const float4*)W;
  const float4* Aw4 = (const float4*)Aw;
  ushort4* wbf4 = (ushort4*)wbf;

  for (int c = 0; c < 4; ++c) {        // 4 chunks of 1024 cols
    __syncthreads();                   // protect AwS reuse (and BoS on c==0)
    #pragma unroll
    for (int t = tid; t < 4096; t += 256) {
      const int r  = t >> 8;
      const int j4 = t & 255;
      ((float4*)AwS)[r * 256 + j4] = Aw4[(size_t)r * 1024 + c * 256 + j4];
    }
    __syncthreads();
    #pragma unroll 4
    for (int i = 0; i < 16; ++i) {
      float4 w = W4[((size_t)(o0 + i) * K_DIM + c * 1024) / 4 + tid];
      float4 acc = {0.f, 0.f, 0.f, 0.f};
      #pragma unroll
      for (int r = 0; r < R_DIM; ++r) {
        const float b = BoS[i * 16 + r];           // LDS broadcast
        const float4 a = ((const float4*)AwS)[r * 256 + tid];
        acc.x += b * a.x; acc.y += b * a.y; acc.z += b * a.z; acc.w += b * a.w;
      }
      float4 v;
      v.x = w.x + 2.f * acc.x; v.y = w.y + 2.f * acc.y;
      v.z = w.z + 2.f * acc.z; v.w = w.w + 2.f * acc.w;
      ss[i] += v.x * v.x + v.y * v.y + v.z * v.z + v.w * v.w;
      ushort4 o;
      o.x = f2bf(v.x); o.y = f2bf(v.y); o.z = f2bf(v.z); o.w = f2bf(v.w);
      wbf4[((size_t)(o0 + i) * K_DIM + c * 1024) / 4 + tid] = o;
    }
  }

  const int lane = tid & 63, wave = tid >> 6;
  #pragma unroll
  for (int i = 0; i < 16; ++i) {
    float s = ss[i];
    #pragma unroll
    for (int off = 32; off > 0; off >>= 1) s += __shfl_down(s, off, 64);
    if (lane == 0) red[i * 4 + wave] = s;
  }
  __syncthreads();
  if (tid < 16) {
    const float s = red[tid * 4] + red[tid * 4 + 1] + red[tid * 4 + 2] + red[tid * 4 + 3];
    scale[o0 + tid] = mag[o0 + tid] / sqrtf(s);
  }
}

// ------------- GEMM: C[m,n] = scale[n] * sum_k A[m,k]*Bt[n,k] -------------
// 128x128x32 tile, 4 waves (2x2), 4x4 of mfma 16x16x32 bf16.
// LDS chunk-XOR swizzle kills the ds_read_b128 bank conflicts:
//   LDS(row r, pos cp) holds global chunk cp ^ ((r>>1)&3); fragment reads at
//   pos fq ^ ((fr>>1)&3). Per 16-lane phase: 2 lanes per 4-bank group = free.
__global__ void __launch_bounds__(256)
dora_gemm(const unsigned short* __restrict__ A,   // [M,K] bf16
          const unsigned short* __restrict__ Bt,  // [N,K] bf16
          const float* __restrict__ scale,        // [N]
          float* __restrict__ C) {                // [M,N] fp32
  __shared__ __align__(16) unsigned short As[128 * 32];
  __shared__ __align__(16) unsigned short Bs[128 * 32];
  const int tid  = threadIdx.x;
  const int lane = tid & 63;
  const int wave = tid >> 6;
  const int bM = blockIdx.y * 128;
  const int bN = blockIdx.x * 128;

  // staging: lane l -> row sr=l>>2 of its 16-row chunk; fetches global chunk
  // gc = (l&3) ^ ((sr>>1)&3) = (l&3) ^ ((l>>3)&3), 8 elems starting at gc*8.
  const int sr = lane >> 2;
  const int sc = (((lane & 3) ^ ((lane >> 3) & 3)) * 8);
  const unsigned short* pa0 = A  + (size_t)(bM + wave * 32 + sr) * K_DIM + sc;
  const unsigned short* pa1 = pa0 + (size_t)16 * K_DIM;
  const unsigned short* pb0 = Bt + (size_t)(bN + wave * 32 + sr) * K_DIM + sc;
  const unsigned short* pb1 = pb0 + (size_t)16 * K_DIM;
  unsigned short* lA0 = &As[wave * 32 * 32];
  unsigned short* lA1 = lA0 + 16 * 32;
  unsigned short* lB0 = &Bs[wave * 32 * 32];
  unsigned short* lB1 = lB0 + 16 * 32;

  const int fr = lane & 15;
  const int fq = lane >> 4;
  const int xr = (fr >> 1) & 3;        // swizzle term for fragment reads
  const int cA = (fq ^ xr) * 8;        // swizzled chunk offset (shorts)
  const int wM = (wave >> 1) * 64;
  const int wN = (wave & 1) * 64;

  f32x4 acc[4][4];
  #pragma unroll
  for (int i = 0; i < 4; ++i)
    #pragma unroll
    for (int j = 0; j < 4; ++j) acc[i][j] = (f32x4){0.f, 0.f, 0.f, 0.f};

  for (int k0 = 0; k0 < K_DIM; k0 += 32) {
    gload16(pa0 + k0, lA0);
    gload16(pa1 + k0, lA1);
    gload16(pb0 + k0, lB0);
    gload16(pb1 + k0, lB1);
    __syncthreads();
    bf16x8 aF[4], bF[4];
    #pragma unroll
    for (int mt = 0; mt < 4; ++mt)
      aF[mt] = *(const bf16x8*)&As[(wM + mt * 16 + fr) * 32 + cA];
    #pragma unroll
    for (int nt = 0; nt < 4; ++nt)
      bF[nt] = *(const bf16x8*)&Bs[(wN + nt * 16 + fr) * 32 + cA];
    #pragma unroll
    for (int mt = 0; mt < 4; ++mt)
      #pragma unroll
      for (int nt = 0; nt < 4; ++nt)
        acc[mt][nt] = __builtin_amdgcn_mfma_f32_16x16x32_bf16(aF[mt], bF[nt], acc[mt][nt], 0, 0, 0);
    __syncthreads();
  }

  // epilogue: C/D layout col=lane&15, row=(lane>>4)*4+reg  [m89]
  float scv[4];
  #pragma unroll
  for (int nt = 0; nt < 4; ++nt) scv[nt] = scale[bN + wN + nt * 16 + fr];
  #pragma unroll
  for (int mt = 0; mt < 4; ++mt) {
    const int m0 = bM + wM + mt * 16 + fq * 4;
    #pragma unroll
    for (int nt = 0; nt < 4; ++nt) {
      const int n = bN + wN + nt * 16 + fr;
      #pragma unroll
      for (int r = 0; r < 4; ++r)
        C[(size_t)(m0 + r) * N_DIM + n] = acc[mt][nt][r] * scv[nt];
    }
  }
}

extern "C" void kernel_launch(void* const* d_in, const int* in_sizes, int n_in,
                              void* d_out, int out_size, void* d_ws, size_t ws_size,
                              hipStream_t stream) {
  const float* x   = (const float*)d_in[0];   // [4,2048,4096]
  const float* W   = (const float*)d_in[1];   // [4096,4096]
  const float* la  = (const float*)d_in[2];   // [16,4096]
  const float* lb  = (const float*)d_in[3];   // [4096,16]
  const float* mag = (const float*)d_in[4];   // [4096]
  float* out = (float*)d_out;

  // ws: x_bf16 (64 MiB) | w_bf16 (32 MiB) | scale (16 KiB)
  unsigned short* xbf = (unsigned short*)d_ws;
  unsigned short* wbf = (unsigned short*)((char*)d_ws + (size_t)M_DIM * K_DIM * 2);
  float* scale = (float*)((char*)d_ws + (size_t)M_DIM * K_DIM * 2 + (size_t)N_DIM * K_DIM * 2);

  prep_kernel<<<PREP_BLOCKS + CAST_BLOCKS, 256, 0, stream>>>(
      (const float4*)x, (ushort4*)xbf, W, la, lb, mag, wbf, scale);
  dim3 grid(N_DIM / 128, M_DIM / 128);
  dora_gemm<<<grid, 256, 0, stream>>>(xbf, wbf, scale, out);
}